// Round 9
// baseline (128.146 us; speedup 1.0000x reference)
//
#include <hip/hip_runtime.h>
#include <math.h>

#define NFULL 4096   // DCT length per row
#define NH    2048   // half-size complex FFT
#define ROWS_PER_BLK 2
#define T     (64 * ROWS_PER_BLK)   // one wave per row

// bijective LDS swizzle: XOR bits[4:7) into bits[1:4). (R5-measured: conflicts -75%)
__device__ __forceinline__ int sw(int i) { return i ^ (((i >> 4) & 7) << 1); }

__device__ __forceinline__ float2 cmul(float2 a, float2 b) {
    return make_float2(a.x * b.x - a.y * b.y, a.x * b.y + a.y * b.x);
}

__device__ __forceinline__ float2 sc(float ang) {
    float s, c;
    __sincosf(ang, &s, &c);
    return make_float2(c, s);
}

// 8-point DFT, no twiddles
__device__ __forceinline__ void dft8(float2 v[8]) {
    const float s = 0.70710678118654752f;
    float2 e0 = v[0], o0 = v[1], e1 = v[2], o1 = v[3];
    float2 e2 = v[4], o2 = v[5], e3 = v[6], o3 = v[7];
    float2 t0 = make_float2(e0.x + e2.x, e0.y + e2.y);
    float2 t1 = make_float2(e0.x - e2.x, e0.y - e2.y);
    float2 t2 = make_float2(e1.x + e3.x, e1.y + e3.y);
    float2 t3 = make_float2(e1.x - e3.x, e1.y - e3.y);
    float2 E0 = make_float2(t0.x + t2.x, t0.y + t2.y);
    float2 E2 = make_float2(t0.x - t2.x, t0.y - t2.y);
    float2 E1 = make_float2(t1.x + t3.y, t1.y - t3.x);
    float2 E3 = make_float2(t1.x - t3.y, t1.y + t3.x);
    float2 u0 = make_float2(o0.x + o2.x, o0.y + o2.y);
    float2 u1 = make_float2(o0.x - o2.x, o0.y - o2.y);
    float2 u2 = make_float2(o1.x + o3.x, o1.y + o3.y);
    float2 u3 = make_float2(o1.x - o3.x, o1.y - o3.y);
    float2 O0 = make_float2(u0.x + u2.x, u0.y + u2.y);
    float2 O2 = make_float2(u0.x - u2.x, u0.y - u2.y);
    float2 O1 = make_float2(u1.x + u3.y, u1.y - u3.x);
    float2 O3 = make_float2(u1.x - u3.y, u1.y + u3.x);
    O1 = make_float2(s * (O1.x + O1.y), s * (O1.y - O1.x));
    O2 = make_float2(O2.y, -O2.x);
    O3 = make_float2(s * (O3.y - O3.x), s * (-O3.x - O3.y));
    v[0] = make_float2(E0.x + O0.x, E0.y + O0.y);
    v[4] = make_float2(E0.x - O0.x, E0.y - O0.y);
    v[1] = make_float2(E1.x + O1.x, E1.y + O1.y);
    v[5] = make_float2(E1.x - O1.x, E1.y - O1.y);
    v[2] = make_float2(E2.x + O2.x, E2.y + O2.y);
    v[6] = make_float2(E2.x - O2.x, E2.y - O2.y);
    v[3] = make_float2(E3.x + O3.x, E3.y + O3.y);
    v[7] = make_float2(E3.x - O3.x, E3.y - O3.y);
}

__device__ __forceinline__ void dft4(float2 v[4]) {
    float2 t0 = make_float2(v[0].x + v[2].x, v[0].y + v[2].y);
    float2 t1 = make_float2(v[0].x - v[2].x, v[0].y - v[2].y);
    float2 t2 = make_float2(v[1].x + v[3].x, v[1].y + v[3].y);
    float2 t3 = make_float2(v[1].x - v[3].x, v[1].y - v[3].y);
    v[0] = make_float2(t0.x + t2.x, t0.y + t2.y);
    v[2] = make_float2(t0.x - t2.x, t0.y - t2.y);
    v[1] = make_float2(t1.x + t3.y, t1.y - t3.x);
    v[3] = make_float2(t1.x - t3.y, t1.y + t3.x);
}

// DCT-II row pass: ONE ROW PER WAVE, wave-private LDS slice, ZERO barriers.
// Wave-internal LDS ordering is guaranteed by lgkmcnt; each wave free-runs so
// DS / VALU / HBM phases of different waves overlap naturally.
// Radix 8,8,8,4 Stockham; each lane: 4 butterflies/stage (32-deep read bursts).
__global__ __launch_bounds__(T, 2) void dct_rows_wave(const float* __restrict__ in,
                                                      const float* __restrict__ expk,
                                                      float* __restrict__ out) {
    __shared__ float2 L[ROWS_PER_BLK][NH];   // 16 KB per wave
    const int wave = threadIdx.x >> 6;
    const int l    = threadIdx.x & 63;
    const int row  = ROWS_PER_BLK * blockIdx.x + wave;
    float2* __restrict__ A = L[wave];
    const float4* __restrict__ src4 = (const float4*)(in + (size_t)row * NFULL);

    float2 v[4][8];
    // ---- stage 1: R=8, Ns=1, global -> LDS; butterfly b = l + 64i ----
    #pragma unroll
    for (int i = 0; i < 4; ++i) {
        const int b = l + 64 * i;
        float4 f0 = src4[b];
        float4 f1 = src4[b + 256];
        float4 f2 = src4[b + 512];
        float4 f3 = src4[b + 768];
        float4 g3 = src4[1023 - b];
        float4 g2 = src4[767 - b];
        float4 g1 = src4[511 - b];
        float4 g0 = src4[255 - b];
        v[i][0] = make_float2(f0.x, f0.z);
        v[i][1] = make_float2(f1.x, f1.z);
        v[i][2] = make_float2(f2.x, f2.z);
        v[i][3] = make_float2(f3.x, f3.z);
        v[i][4] = make_float2(g3.w, g3.y);
        v[i][5] = make_float2(g2.w, g2.y);
        v[i][6] = make_float2(g1.w, g1.y);
        v[i][7] = make_float2(g0.w, g0.y);
    }
    #pragma unroll
    for (int i = 0; i < 4; ++i) {
        dft8(v[i]);
        const int b = l + 64 * i;
        #pragma unroll
        for (int r = 0; r < 8; ++r) A[sw(8 * b + r)] = v[i][r];
    }

    // ---- stage 2: R=8, Ns=8; q = l+64i; (q&7) == (l&7) -> twiddles i-invariant ----
    {
        #pragma unroll
        for (int i = 0; i < 4; ++i)
            #pragma unroll
            for (int r = 0; r < 8; ++r) v[i][r] = A[sw(l + 64 * i + 256 * r)];
        const float a = -(float)M_PI / 32.0f * (float)(l & 7);
        float2 w1 = sc(a), w2 = sc(2.0f * a), w4 = sc(4.0f * a);
        float2 w3 = cmul(w1, w2), w5 = cmul(w1, w4), w6 = cmul(w2, w4);
        float2 w7 = cmul(w3, w4);
        #pragma unroll
        for (int i = 0; i < 4; ++i) {
            v[i][1] = cmul(v[i][1], w1); v[i][2] = cmul(v[i][2], w2);
            v[i][3] = cmul(v[i][3], w3); v[i][4] = cmul(v[i][4], w4);
            v[i][5] = cmul(v[i][5], w5); v[i][6] = cmul(v[i][6], w6);
            v[i][7] = cmul(v[i][7], w7);
            dft8(v[i]);
        }
        #pragma unroll
        for (int i = 0; i < 4; ++i) {
            const int q = l + 64 * i;
            const int d = ((q >> 3) << 6) + (q & 7);
            #pragma unroll
            for (int r = 0; r < 8; ++r) A[sw(d + 8 * r)] = v[i][r];
        }
    }

    // ---- stage 3: R=8, Ns=64; (q&63) == l -> twiddles i-invariant ----
    {
        #pragma unroll
        for (int i = 0; i < 4; ++i)
            #pragma unroll
            for (int r = 0; r < 8; ++r) v[i][r] = A[sw(l + 64 * i + 256 * r)];
        const float a = -(float)M_PI / 256.0f * (float)l;
        float2 w1 = sc(a), w2 = sc(2.0f * a), w4 = sc(4.0f * a);
        float2 w3 = cmul(w1, w2), w5 = cmul(w1, w4), w6 = cmul(w2, w4);
        float2 w7 = cmul(w3, w4);
        #pragma unroll
        for (int i = 0; i < 4; ++i) {
            v[i][1] = cmul(v[i][1], w1); v[i][2] = cmul(v[i][2], w2);
            v[i][3] = cmul(v[i][3], w3); v[i][4] = cmul(v[i][4], w4);
            v[i][5] = cmul(v[i][5], w5); v[i][6] = cmul(v[i][6], w6);
            v[i][7] = cmul(v[i][7], w7);
            dft8(v[i]);
        }
        #pragma unroll
        for (int i = 0; i < 4; ++i) {
            const int q = l + 64 * i;
            const int d = ((q >> 6) << 9) + (q & 63);
            #pragma unroll
            for (int r = 0; r < 8; ++r) A[sw(d + 64 * r)] = v[i][r];
        }
    }

    // ---- stage 4: R=4, Ns=512; q = l + 64i, i<8; in-place indices ----
    {
        float2 u[8][4];
        #pragma unroll
        for (int i = 0; i < 8; ++i)
            #pragma unroll
            for (int r = 0; r < 4; ++r) u[i][r] = A[sw(l + 64 * i + 512 * r)];
        #pragma unroll
        for (int i = 0; i < 8; ++i) {
            const int q = l + 64 * i;
            const float a = -(float)M_PI / 1024.0f * (float)q;
            float2 w1 = sc(a), w2 = sc(2.0f * a);
            float2 w3 = cmul(w1, w2);
            u[i][1] = cmul(u[i][1], w1);
            u[i][2] = cmul(u[i][2], w2);
            u[i][3] = cmul(u[i][3], w3);
            dft4(u[i]);
        }
        #pragma unroll
        for (int i = 0; i < 8; ++i)
            #pragma unroll
            for (int r = 0; r < 4; ++r) A[sw(l + 64 * i + 512 * r)] = u[i][r];
    }

    // ---- epilogue: rfft untangle + DCT twiddle; k = l + 64i ----
    const float2* __restrict__ ek = (const float2*)expk;
    float* __restrict__ dst = out + (size_t)row * NFULL;
    #pragma unroll
    for (int i = 0; i < 32; ++i) {
        const int k = l + 64 * i;
        if (k == 0) {
            float2 z0 = A[sw(0)];
            dst[0]  = ek[0].x * (z0.x + z0.y);
            dst[NH] = ek[NH].x * (z0.x - z0.y);
        } else {
            float2 Zk = A[sw(k)];
            float2 Zr = A[sw(NH - k)];
            float2 E = make_float2(0.5f * (Zk.x + Zr.x), 0.5f * (Zk.y - Zr.y));
            float2 O = make_float2(0.5f * (Zk.y + Zr.y), 0.5f * (Zr.x - Zk.x));
            float2 uu = sc(-(float)M_PI / 2048.0f * (float)k);
            float2 Y = make_float2(E.x + uu.x * O.x - uu.y * O.y,
                                   E.y + uu.x * O.y + uu.y * O.x);
            float2 wk = ek[k];
            dst[k] = wk.x * Y.x - wk.y * Y.y;
            float2 wn = ek[NFULL - k];
            dst[NFULL - k] = wn.x * Y.x + wn.y * Y.y;
        }
    }
}

// 32x32 LDS-tiled transpose
__global__ __launch_bounds__(256) void transpose4k(const float* __restrict__ in,
                                                   float* __restrict__ out) {
    __shared__ float tile[32][33];
    const int x0 = blockIdx.x * 32;
    const int y0 = blockIdx.y * 32;
    const int tx = threadIdx.x & 31;
    const int ty = threadIdx.x >> 5;

    #pragma unroll
    for (int i = 0; i < 32; i += 8)
        tile[ty + i][tx] = in[(size_t)(y0 + ty + i) * NFULL + (x0 + tx)];
    __syncthreads();
    #pragma unroll
    for (int i = 0; i < 32; i += 8)
        out[(size_t)(x0 + ty + i) * NFULL + (y0 + tx)] = tile[tx][ty + i];
}

extern "C" void kernel_launch(void* const* d_in, const int* in_sizes, int n_in,
                              void* d_out, int out_size, void* d_ws, size_t ws_size,
                              hipStream_t stream) {
    const float* x     = (const float*)d_in[0];
    const float* expkM = (const float*)d_in[1];
    const float* expkN = (const float*)d_in[2];
    float* out = (float*)d_out;
    float* ws1 = (float*)d_ws;

    dct_rows_wave<<<NFULL / ROWS_PER_BLK, T, 0, stream>>>(x, expkN, ws1);
    transpose4k<<<dim3(128, 128), 256, 0, stream>>>(ws1, out);
    dct_rows_wave<<<NFULL / ROWS_PER_BLK, T, 0, stream>>>(out, expkM, ws1);
    transpose4k<<<dim3(128, 128), 256, 0, stream>>>(ws1, out);
}